// Round 3
// baseline (87.346 us; speedup 1.0000x reference)
//
#include <hip/hip_runtime.h>

// Problem constants: N=512, L=16, HOP=8, M=8, C=2, K=6000
#define NN   512
#define LL   16
#define HOPP 8
#define MM   8
#define CC   2
#define KK   6000
#define TT   ((KK - 1) * HOPP + LL)   // 48008
#define KW   94                       // k-columns per block
#define NACT 47                       // active lanes (2 k per lane)

// Block: 512 threads = 8 waves. Wave q handles n in [q*64, q*64+64).
// Lane t handles k = kb*94 + {2t, 2t+1} (float2 loads). Each thread fuses
// both c. W staged in LDS, read as float4 (ds_read_b128, wave-uniform
// broadcast). Tree-reduce 8 waves -> wave 0, then in-register overlap-add
// with 2-term commutative atomics at block seams (deterministic).
__global__ __launch_bounds__(512, 4) void decoder_fused_kernel(
    const float* __restrict__ inputs,    // [M, N, K]
    const float* __restrict__ est_mask,  // [M, C, N, K]
    const float* __restrict__ W,         // [N, L]
    float* __restrict__ out)             // [M, C, T], pre-zeroed
{
    // union: W stage (8192 floats) | reduce buffer (act4: 4*64*33=8448,
    // act2: 2*64*67=8576, act1: 64*67)
    __shared__ float smem[8576];         // 34.3 KB

    const int tid = threadIdx.x;
    const int t   = tid & 63;            // lane
    const int q   = tid >> 6;            // wave id, 0..7
    const int kb  = blockIdx.x;          // 0..63
    const int m   = blockIdx.y;          // 0..7

    // ---- stage W into LDS (2048 float4, coalesced) ----
    for (int j = tid; j < (NN * LL / 4); j += 512) {
        reinterpret_cast<float4*>(smem)[j] =
            reinterpret_cast<const float4*>(W)[j];
    }
    __syncthreads();

    const int kA  = kb * KW + 2 * t;                 // even
    const int kAc = (kA < KK - 1) ? kA : (KK - 2);   // clamp to valid float2

    const float* base_in = inputs   + ((size_t)m * NN + q * 64) * KK + kAc;
    const float* base_m0 = est_mask + (((size_t)m * CC + 0) * NN + q * 64) * KK + kAc;
    const float* base_m1 = base_m0 + (size_t)NN * KK;

    float a0A[LL], a0B[LL], a1A[LL], a1B[LL];        // acc[c][kA/kB][l]
    #pragma unroll
    for (int l = 0; l < LL; ++l) { a0A[l] = 0.f; a0B[l] = 0.f; a1A[l] = 0.f; a1B[l] = 0.f; }

    const float4* wrow4 = reinterpret_cast<const float4*>(&smem[q * 64 * LL]);

    // ---- main loop: 64 n-rows per wave ----
    #pragma unroll 2
    for (int i = 0; i < 64; ++i) {
        const float2 vin = *reinterpret_cast<const float2*>(base_in + (size_t)i * KK);
        const float2 vm0 = *reinterpret_cast<const float2*>(base_m0 + (size_t)i * KK);
        const float2 vm1 = *reinterpret_cast<const float2*>(base_m1 + (size_t)i * KK);
        const float x0A = vin.x * vm0.x, x0B = vin.y * vm0.y;
        const float x1A = vin.x * vm1.x, x1B = vin.y * vm1.y;
        #pragma unroll
        for (int p = 0; p < 4; ++p) {
            const float4 w  = wrow4[i * 4 + p];      // ds_read_b128, broadcast
            const float wl[4] = {w.x, w.y, w.z, w.w};
            #pragma unroll
            for (int u = 0; u < 4; ++u) {
                const int l = p * 4 + u;
                a0A[l] = fmaf(x0A, wl[u], a0A[l]);
                a0B[l] = fmaf(x0B, wl[u], a0B[l]);
                a1A[l] = fmaf(x1A, wl[u], a1A[l]);
                a1B[l] = fmaf(x1B, wl[u], a1B[l]);
            }
        }
    }

    // ---- tree-reduce 8 waves -> wave 0 ----
    __syncthreads();   // everyone done reading W

    // act=4, phase c=0 (32 floats/thread, stride 33 -> 2-way free)
    if (q >= 4) {
        float* dst = &smem[((q - 4) * 64 + t) * 33];
        #pragma unroll
        for (int l = 0; l < LL; ++l) { dst[l] = a0A[l]; dst[16 + l] = a0B[l]; }
    }
    __syncthreads();
    if (q < 4) {
        const float* s = &smem[(q * 64 + t) * 33];
        #pragma unroll
        for (int l = 0; l < LL; ++l) { a0A[l] += s[l]; a0B[l] += s[16 + l]; }
    }
    __syncthreads();
    // act=4, phase c=1
    if (q >= 4) {
        float* dst = &smem[((q - 4) * 64 + t) * 33];
        #pragma unroll
        for (int l = 0; l < LL; ++l) { dst[l] = a1A[l]; dst[16 + l] = a1B[l]; }
    }
    __syncthreads();
    if (q < 4) {
        const float* s = &smem[(q * 64 + t) * 33];
        #pragma unroll
        for (int l = 0; l < LL; ++l) { a1A[l] += s[l]; a1B[l] += s[16 + l]; }
    }
    __syncthreads();
    // act=2, both c (64 floats/thread, stride 67 -> 2-way free)
    if (q == 2 || q == 3) {
        float* dst = &smem[((q - 2) * 64 + t) * 67];
        #pragma unroll
        for (int l = 0; l < LL; ++l) {
            dst[l] = a0A[l]; dst[16 + l] = a0B[l];
            dst[32 + l] = a1A[l]; dst[48 + l] = a1B[l];
        }
    }
    __syncthreads();
    if (q < 2) {
        const float* s = &smem[(q * 64 + t) * 67];
        #pragma unroll
        for (int l = 0; l < LL; ++l) {
            a0A[l] += s[l]; a0B[l] += s[16 + l];
            a1A[l] += s[32 + l]; a1B[l] += s[48 + l];
        }
    }
    __syncthreads();
    // act=1
    if (q == 1) {
        float* dst = &smem[t * 67];
        #pragma unroll
        for (int l = 0; l < LL; ++l) {
            dst[l] = a0A[l]; dst[16 + l] = a0B[l];
            dst[32 + l] = a1A[l]; dst[48 + l] = a1B[l];
        }
    }
    __syncthreads();

    if (q == 0) {
        {
            const float* s = &smem[t * 67];
            #pragma unroll
            for (int l = 0; l < LL; ++l) {
                a0A[l] += s[l]; a0B[l] += s[16 + l];
                a1A[l] += s[32 + l]; a1B[l] += s[48 + l];
            }
        }

        // ---- overlap-and-add ----
        // prev-hi for kA comes from lane t-1's kB hi half (shfl before branch)
        float ph0[8], ph1[8];
        #pragma unroll
        for (int j = 0; j < 8; ++j) {
            ph0[j] = __shfl_up(a0B[8 + j], 1);
            ph1[j] = __shfl_up(a1B[8 + j], 1);
        }

        if (t < NACT && kA < KK) {
            float* o0 = out + ((size_t)m * CC + 0) * TT + 8 * kA;
            float* o1 = out + ((size_t)m * CC + 1) * TT + 8 * kA;

            if (t == 0) {
                // lo of first frame in block: pairs with prev block's hi atomic
                #pragma unroll
                for (int j = 0; j < 8; ++j) {
                    atomicAdd(&o0[j], a0A[j]);
                    atomicAdd(&o1[j], a1A[j]);
                }
            } else {
                #pragma unroll
                for (int j = 0; j < 8; ++j) {
                    o0[j] = a0A[j] + ph0[j];
                    o1[j] = a1A[j] + ph1[j];
                }
            }
            // kB lo: both terms in-lane
            #pragma unroll
            for (int j = 0; j < 8; ++j) {
                o0[8 + j] = a0B[j] + a0A[8 + j];
                o1[8 + j] = a1B[j] + a1A[8 + j];
            }
            // kB hi: consumed by lane t+1 unless block seam / global tail
            const int kB = kA + 1;
            if (t == NACT - 1 || kB == KK - 1) {
                #pragma unroll
                for (int j = 0; j < 8; ++j) {
                    atomicAdd(&o0[16 + j], a0B[8 + j]);
                    atomicAdd(&o1[16 + j], a1B[8 + j]);
                }
            }
        }
    }
}

extern "C" void kernel_launch(void* const* d_in, const int* in_sizes, int n_in,
                              void* d_out, int out_size, void* d_ws, size_t ws_size,
                              hipStream_t stream) {
    const float* inputs   = (const float*)d_in[0];  // [8, 512, 6000]
    const float* est_mask = (const float*)d_in[1];  // [8, 2, 512, 6000]
    const float* W        = (const float*)d_in[2];  // [512, 16]
    float*       out      = (float*)d_out;          // [8, 2, 48008]

    hipMemsetAsync(out, 0, (size_t)out_size * sizeof(float), stream);

    dim3 grid((KK + KW - 1) / KW, MM);   // (64, 8) = 512 blocks = 2/CU exactly
    decoder_fused_kernel<<<grid, 512, 0, stream>>>(inputs, est_mask, W, out);
}

// Round 4
// 64.963 us; speedup vs baseline: 1.3445x; 1.3445x over previous
//
#include <hip/hip_runtime.h>

// Problem constants: N=512, L=16, HOP=8, M=8, C=2, K=6000
#define NN   512
#define LL   16
#define MM   8
#define CC   2
#define KK   6000
#define TT   ((KK - 1) * 8 + 16)      // 48008
#define KW   64                       // k-columns per block (256B aligned tiles)
#define NCH  32                       // n-rows per chunk
#define NC   (NN / NCH)               // 16 chunks
#define ROWB (KK * 4)                 // 24000 bytes per n-row
#define TENS_B (NCH * KW * 4)         // 8192 B per tensor per buffer
#define BUF_B  (3 * TENS_B)           // 24576 B per buffer

typedef __attribute__((address_space(3))) void       lds_v;
typedef __attribute__((address_space(1))) const void glob_v;

// Block: 512 threads = 8 waves, k = kb*64 + lane. inputs/m0/m1 staged into
// LDS by global_load_lds (16B/lane, 1KB/instr) double-buffered in 32-row
// chunks: issue(c+1) -> compute(c) -> __syncthreads (drain overlapped with
// compute since BW-time/chunk > compute-time/chunk). W via wave-uniform
// scalar loads. Tree-reduce 8 waves -> wave 0, in-register overlap-add,
// 2-term commutative atomics at block seams (deterministic).
__global__ __launch_bounds__(512, 2) void decoder_dma_kernel(
    const float* __restrict__ inputs,    // [M, N, K]
    const float* __restrict__ est_mask,  // [M, C, N, K]
    const float* __restrict__ W,         // [N, L]
    float* __restrict__ out)             // [M, C, T], pre-zeroed
{
    __shared__ __align__(16) char lds[2 * BUF_B];   // 48 KB

    const int tid = threadIdx.x;
    const int t   = tid & 63;                        // lane = k within tile
    const int wq  = __builtin_amdgcn_readfirstlane(tid >> 6);  // wave id 0..7
    const int kb  = blockIdx.x;                      // 0..93
    const int m   = blockIdx.y;                      // 0..7

    // per-lane DMA source offset: lane covers row (t>>4) of a 4-row group,
    // 16B k-slice (t&15). Clamp column for the kb=93 tail (k>=6000 lanes
    // load garbage; their results are discarded by the k<KK guard below).
    const int lane_r = t >> 4;
    int cb = kb * 256 + (t & 15) * 16;
    if (cb > ROWB - 16) cb = ROWB - 16;
    const size_t lane_off = (size_t)lane_r * ROWB + cb;

    const char* tb0 = (const char*)inputs   + (size_t)m * NN * ROWB;
    const char* tb1 = (const char*)est_mask + (size_t)(m * CC + 0) * NN * ROWB;
    const char* tb2 = tb1 + (size_t)NN * ROWB;
    const char* tb[3] = { tb0, tb1, tb2 };

    // wave wq issues instrs idx = wq*3 + j (j=0..2), idx = tens*8 + group.
    // group g covers rows c*32 + g*4 .. +3; LDS dest = buf + tens*8K + g*1K,
    // lane auto-offset 16B -> linear [tens][row][k] tile.
    auto issue = [&](int c, int bsel) {
        char* bb = lds + bsel * BUF_B;
        #pragma unroll
        for (int j = 0; j < 3; ++j) {
            const int idx  = wq * 3 + j;   // 0..23
            const int tens = idx >> 3;
            const int g    = idx & 7;
            const char* gsrc = tb[tens] + (size_t)(c * NCH + g * 4) * ROWB + lane_off;
            lds_v* ldst = (lds_v*)(bb + tens * TENS_B + g * 1024);
            __builtin_amdgcn_global_load_lds((glob_v*)gsrc, ldst, 16, 0, 0);
        }
    };

    float acc0[LL], acc1[LL];
    #pragma unroll
    for (int l = 0; l < LL; ++l) { acc0[l] = 0.f; acc1[l] = 0.f; }

    issue(0, 0);
    __syncthreads();

    for (int c = 0; c < NC; ++c) {
        if (c + 1 < NC) issue(c + 1, (c + 1) & 1);   // in flight during compute

        const float* Lin = (const float*)(lds + (c & 1) * BUF_B);
        const float* Lm0 = Lin + 2048;
        const float* Lm1 = Lin + 4096;

        #pragma unroll
        for (int rr = 0; rr < 4; ++rr) {
            const int r = wq * 4 + rr;         // row in chunk (uniform)
            const int n = c * NCH + r;         // global n (uniform) -> s_load W
            float wv[LL];
            *reinterpret_cast<float4*>(&wv[0])  = *(const float4*)(W + n * LL + 0);
            *reinterpret_cast<float4*>(&wv[4])  = *(const float4*)(W + n * LL + 4);
            *reinterpret_cast<float4*>(&wv[8])  = *(const float4*)(W + n * LL + 8);
            *reinterpret_cast<float4*>(&wv[12]) = *(const float4*)(W + n * LL + 12);

            const float xin = Lin[r * 64 + t];
            const float xm0 = Lm0[r * 64 + t];
            const float xm1 = Lm1[r * 64 + t];
            const float x0 = xin * xm0;
            const float x1 = xin * xm1;
            #pragma unroll
            for (int l = 0; l < LL; ++l) {
                acc0[l] = fmaf(x0, wv[l], acc0[l]);
                acc1[l] = fmaf(x1, wv[l], acc1[l]);
            }
        }
        __syncthreads();   // drains c+1's DMA (overlapped) + guards buf reuse
    }

    // ---- tree-reduce 8 waves -> wave 0 (stride 33 -> 2-way = free) ----
    float* sm = (float*)lds;
    if (wq >= 4) {
        float* d = &sm[((wq - 4) * 64 + t) * 33];
        #pragma unroll
        for (int l = 0; l < LL; ++l) { d[l] = acc0[l]; d[16 + l] = acc1[l]; }
    }
    __syncthreads();
    if (wq < 4) {
        const float* s = &sm[(wq * 64 + t) * 33];
        #pragma unroll
        for (int l = 0; l < LL; ++l) { acc0[l] += s[l]; acc1[l] += s[16 + l]; }
    }
    __syncthreads();
    if (wq == 2 || wq == 3) {
        float* d = &sm[((wq - 2) * 64 + t) * 33];
        #pragma unroll
        for (int l = 0; l < LL; ++l) { d[l] = acc0[l]; d[16 + l] = acc1[l]; }
    }
    __syncthreads();
    if (wq < 2) {
        const float* s = &sm[(wq * 64 + t) * 33];
        #pragma unroll
        for (int l = 0; l < LL; ++l) { acc0[l] += s[l]; acc1[l] += s[16 + l]; }
    }
    __syncthreads();
    if (wq == 1) {
        float* d = &sm[t * 33];
        #pragma unroll
        for (int l = 0; l < LL; ++l) { d[l] = acc0[l]; d[16 + l] = acc1[l]; }
    }
    __syncthreads();

    if (wq == 0) {
        {
            const float* s = &sm[t * 33];
            #pragma unroll
            for (int l = 0; l < LL; ++l) { acc0[l] += s[l]; acc1[l] += s[16 + l]; }
        }

        // ---- overlap-and-add: out[8k+j] = lo_k[j] + hi_{k-1}[j] ----
        const int k = kb * KW + t;
        float ph0[8], ph1[8];
        #pragma unroll
        for (int j = 0; j < 8; ++j) {
            ph0[j] = __shfl_up(acc0[8 + j], 1);
            ph1[j] = __shfl_up(acc1[8 + j], 1);
        }

        if (k < KK) {
            float* o0 = out + ((size_t)m * CC + 0) * TT + 8 * k;
            float* o1 = out + ((size_t)m * CC + 1) * TT + 8 * k;

            if (t == 0) {
                // previous frame owned by another block -> atomic (zeroed base)
                #pragma unroll
                for (int j = 0; j < 8; ++j) {
                    atomicAdd(&o0[j], acc0[j]);
                    atomicAdd(&o1[j], acc1[j]);
                }
            } else {
                #pragma unroll
                for (int j = 0; j < 8; ++j) {
                    o0[j] = acc0[j] + ph0[j];
                    o1[j] = acc1[j] + ph1[j];
                }
            }
            if (t == 63 || k == KK - 1) {
                // hi half consumed by next block (or the tail) -> atomic
                #pragma unroll
                for (int j = 0; j < 8; ++j) {
                    atomicAdd(&o0[8 + j], acc0[8 + j]);
                    atomicAdd(&o1[8 + j], acc1[8 + j]);
                }
            }
        }
    }
}

extern "C" void kernel_launch(void* const* d_in, const int* in_sizes, int n_in,
                              void* d_out, int out_size, void* d_ws, size_t ws_size,
                              hipStream_t stream) {
    const float* inputs   = (const float*)d_in[0];  // [8, 512, 6000]
    const float* est_mask = (const float*)d_in[1];  // [8, 2, 512, 6000]
    const float* W        = (const float*)d_in[2];  // [512, 16]
    float*       out      = (float*)d_out;          // [8, 2, 48008]

    hipMemsetAsync(out, 0, (size_t)out_size * sizeof(float), stream);

    dim3 grid((KK + KW - 1) / KW, MM);   // (94, 8) = 752 blocks of 512 threads
    decoder_dma_kernel<<<grid, 512, 0, stream>>>(inputs, est_mask, W, out);
}